// Round 3
// baseline (600.517 us; speedup 1.0000x reference)
//
#include <hip/hip_runtime.h>

typedef __attribute__((ext_vector_type(8))) short short8;
typedef __attribute__((ext_vector_type(4))) short short4v;
typedef __attribute__((ext_vector_type(4))) float floatx4;
typedef unsigned short u16;

#define MFMA16(a,b,c) __builtin_amdgcn_mfma_f32_16x16x32_bf16(a,b,c,0,0,0)

typedef const __attribute__((address_space(1))) void* gas1;
typedef __attribute__((address_space(3))) void* las3;
static __device__ __forceinline__ void glds16(const void* g, void* l){
  __builtin_amdgcn_global_load_lds((gas1)g, (las3)l, 16, 0, 0);
}

// fp32 -> bf16 round-to-nearest-even
static __device__ __forceinline__ u16 f2b(float f){
  union { float f; unsigned int u; } c; c.f = f;
  unsigned int u = c.u;
  u += 0x7fffu + ((u >> 16) & 1u);
  return (u16)(u >> 16);
}

// ---------------- weight transpose + fp32->bf16: W[KxN] -> Wt[NxK] ----------------
__global__ __launch_bounds__(256) void transpose_cvt(
    const float* __restrict__ W, u16* __restrict__ Wt, int K, int N){
  __shared__ float tile[32][33];
  const int tx = threadIdx.x & 31;
  const int ty = threadIdx.x >> 5;
  const int nx = blockIdx.x * 32, kx = blockIdx.y * 32;
  #pragma unroll
  for (int i = ty; i < 32; i += 8)
    tile[i][tx] = W[(size_t)(kx + i) * N + nx + tx];
  __syncthreads();
  #pragma unroll
  for (int i = ty; i < 32; i += 8)
    Wt[(size_t)(nx + i) * K + kx + tx] = f2b(tile[tx][i]);
}

// ---------------- layernorm fp32 -> bf16, C=1024, 1 block/row ----------------
__global__ __launch_bounds__(256) void ln_kernel(
    const float* __restrict__ x, const float* __restrict__ g,
    const float* __restrict__ b, u16* __restrict__ out){
  const int row = blockIdx.x, tid = threadIdx.x;
  const float4 v = reinterpret_cast<const float4*>(x + (size_t)row * 1024)[tid];
  float s  = v.x + v.y + v.z + v.w;
  float s2 = v.x*v.x + v.y*v.y + v.z*v.z + v.w*v.w;
  #pragma unroll
  for (int off = 1; off < 64; off <<= 1){
    s  += __shfl_xor(s,  off);
    s2 += __shfl_xor(s2, off);
  }
  __shared__ float red[8];
  const int wave = tid >> 6, lane = tid & 63;
  if (lane == 0){ red[wave] = s; red[4 + wave] = s2; }
  __syncthreads();
  s  = red[0] + red[1] + red[2] + red[3];
  s2 = red[4] + red[5] + red[6] + red[7];
  const float mu  = s * (1.f/1024.f);
  const float var = s2 * (1.f/1024.f) - mu * mu;
  const float rs  = rsqrtf(var + 1e-5f);
  const float4 gg = reinterpret_cast<const float4*>(g)[tid];
  const float4 bb = reinterpret_cast<const float4*>(b)[tid];
  ushort4 o;
  o.x = f2b((v.x - mu) * rs * gg.x + bb.x);
  o.y = f2b((v.y - mu) * rs * gg.y + bb.y);
  o.z = f2b((v.z - mu) * rs * gg.z + bb.z);
  o.w = f2b((v.w - mu) * rs * gg.w + bb.w);
  reinterpret_cast<ushort4*>(out + (size_t)row * 1024)[tid] = o;
}

// ---------------- bias concat for fused QKV ----------------
__global__ __launch_bounds__(256) void bias_concat(
    const float* __restrict__ bq, const float* __restrict__ bk,
    const float* __restrict__ bv, float* __restrict__ o){
  const int i = blockIdx.x * 256 + threadIdx.x;
  if (i < 1024) o[i] = bq[i];
  else if (i < 2048) o[i] = bk[i - 1024];
  else if (i < 3072) o[i] = bv[i - 2048];
}

// ---------------- GEMM: 256x256 tile, BK=64, depth-3 8-phase schedule ----------------
// A: MxK bf16; Bt: NxK bf16; out = epilogue(A @ Bt^T + bias [+res]); K % 128 == 0.
// 8 waves as 2(M) x 4(N); per-wave output 128x64 (acc[8][4] 16x16 fragments).
// LDS per buffer: [kh 0/1][256 rows][32 cols], XOR chunk swizzle (0-conflict).
// B rows PERMUTED at staging (packed epilogue stores).
// Pairs per K-tile (2 glds16 each): P0=A.kh0 P1=B.kh0 P2=A.kh1 P3=B.kh1.
// DEPTH-3 pipeline: stage pair 3-6 phases before the wait that vouches for it;
// waits ONLY at ph3/ph7, vmcnt(4) (= 2 newest pairs may remain in flight).
//   ph0: read buf0.kh0 (q0)   stage (t+1).P2->buf1     [buf1 reads closed prev ph7]
//   ph1: read buf0.kh0 (q1)   stage (t+1).P3->buf1
//   ph2: read buf0.kh1 (q0)   stage (t+2).P0->buf0     [buf0.kh0 reads closed ph1]
//   ph3: read buf0.kh1 (q1)   stage (t+2).P1->buf0  WAITV(4): tile t+1 fully landed
//   ph4: read buf1.kh0 (q0)   stage (t+2).P2->buf0     [buf0.kh1 reads closed ph3]
//   ph5: read buf1.kh0 (q1)   stage (t+2).P3->buf0
//   ph6: read buf1.kh1 (q0)   stage (t+3).P0->buf1     [buf1.kh0 reads closed ph5]
//   ph7: read buf1.kh1 (q1)   stage (t+3).P1->buf1  WAITV(4): tile t+2 fully landed
// Wait audit: at ph3, outstanding <= {prev leftover (t+1)P0,P1} + ph0-3 stages = 12
//   loads; vmcnt(4) leaves newest 2 pairs ((t+2)P0,P1) -> ALL of t+1 landed. Same at ph7.
// XCD swizzle (nwg%8==0 for all grids): each XCD gets a contiguous work chunk ->
// B panels L2-resident per XCD, A served from L3 instead of HBM re-fetch.
template<bool GELU, bool RES, bool OUTBF, bool QKVMODE>
__global__ __launch_bounds__(512) void gemm256(
    const u16* __restrict__ A, const u16* __restrict__ Bt,
    const float* __restrict__ bias,
    const float* __restrict__ res,
    float* __restrict__ outF, u16* __restrict__ outB,
    u16* __restrict__ vtb,
    int M, int N, int K)
{
  __shared__ __attribute__((aligned(16))) u16 sA[2][2][256 * 32];
  __shared__ __attribute__((aligned(16))) u16 sB[2][2][256 * 32];
  const int tid  = threadIdx.x;
  const int wave = tid >> 6, lane = tid & 63, ql = lane >> 4, l16 = lane & 15;
  const int wr = wave >> 2, wc = wave & 3;

  // bijective XCD-contiguous remap (requires nwg % 8 == 0; true for all call sites)
  const int nwg = gridDim.x * gridDim.y;
  int lin = blockIdx.y * gridDim.x + blockIdx.x;
  lin = (lin & 7) * (nwg >> 3) + (lin >> 3);
  const int m0 = (lin % gridDim.x) * 256, n0 = (lin / gridDim.x) * 256;

  const int scol = ((lane & 3) ^ ((lane >> 3) & 3)) * 8;
  const u16* aBase = A  + (size_t)(m0 + wave*16 + (lane >> 2)) * K + scol;
  const u16* bBase = Bt + (size_t)(n0 + wr*64 + 4*(lane >> 2) + wc) * K + scol;
  const size_t hK = (size_t)128 * K;
  const int qx = (ql ^ ((l16 >> 1) & 3)) * 8;

  floatx4 acc[8][4];
  #pragma unroll
  for (int i = 0; i < 8; i++)
    #pragma unroll
    for (int nt = 0; nt < 4; nt++) acc[i][nt] = floatx4{0.f,0.f,0.f,0.f};
  short8 af[4], bf[4];

// stage one load-pair P_ of tile T_ into buffer B_ (2 x glds16)
#define STG2(B_, T_, P_) do { \
    const size_t ko_ = (size_t)(T_) * 64 + (((P_) >> 1) ? 32 : 0); \
    if ((P_) & 1){ \
      glds16(bBase + ko_,      &sB[B_][(P_)>>1][wave*512]); \
      glds16(bBase + ko_ + hK, &sB[B_][(P_)>>1][4096 + wave*512]); \
    } else { \
      glds16(aBase + ko_,      &sA[B_][(P_)>>1][wave*512]); \
      glds16(aBase + ko_ + hK, &sA[B_][(P_)>>1][4096 + wave*512]); \
    } \
  } while(0)
#define LDA(B_, KH_, Q_) do { \
    _Pragma("unroll") \
    for (int ii_ = 0; ii_ < 4; ii_++) \
      af[ii_] = *reinterpret_cast<const short8*>( \
          &sA[B_][KH_][(wr*128 + (Q_)*64 + ii_*16 + l16)*32 + qx]); \
  } while(0)
#define LDB(B_, KH_) do { \
    _Pragma("unroll") \
    for (int nt_ = 0; nt_ < 4; nt_++) \
      bf[nt_] = *reinterpret_cast<const short8*>( \
          &sB[B_][KH_][(wc*64 + nt_*16 + l16)*32 + qx]); \
  } while(0)
#define MM(Q_) do { \
    __builtin_amdgcn_s_setprio(1); \
    _Pragma("unroll") \
    for (int ii_ = 0; ii_ < 4; ii_++) \
      _Pragma("unroll") \
      for (int nt_ = 0; nt_ < 4; nt_++) \
        acc[(Q_)*4 + ii_][nt_] = MFMA16(af[ii_], bf[nt_], acc[(Q_)*4 + ii_][nt_]); \
    __builtin_amdgcn_s_setprio(0); \
  } while(0)
#define BAR() do { asm volatile("" ::: "memory"); \
    __builtin_amdgcn_s_barrier(); asm volatile("" ::: "memory"); } while(0)
#define WAITV(N_) asm volatile("s_waitcnt vmcnt(" #N_ ")" ::: "memory")

  const int ntile = K >> 6;       // K % 128 == 0 -> even tile count >= 2
  // prologue: tile0 all pairs + tile1 P0,P1 (pipeline fill, depth 3)
  STG2(0, 0, 0); STG2(0, 0, 1); STG2(0, 0, 2); STG2(0, 0, 3);
  STG2(1, 1, 0); STG2(1, 1, 1);
  WAITV(4);                       // tile0 fully landed; tile1 kh0 in flight
  BAR();

  #pragma unroll 1
  for (int t = 0; t < ntile; t += 2){
    const bool more = (t + 2 < ntile);
    // ph0: buf0 kh0 q0 | stage (t+1).P2 -> buf1 A.kh1
    LDB(0,0); LDA(0,0,0); STG2(1, t+1, 2);
    BAR(); MM(0); BAR();
    // ph1: buf0 kh0 q1 | stage (t+1).P3 -> buf1 B.kh1
    LDA(0,0,1); STG2(1, t+1, 3);
    BAR(); MM(1); BAR();
    // ph2: buf0 kh1 q0 | stage (t+2).P0 -> buf0 A.kh0
    LDB(0,1); LDA(0,1,0); if (more) STG2(0, t+2, 0);
    BAR(); MM(0); BAR();
    // ph3: buf0 kh1 q1 | stage (t+2).P1 -> buf0 B.kh0 | vouch tile t+1
    LDA(0,1,1);
    if (more){ STG2(0, t+2, 1); WAITV(4); } else { WAITV(0); }
    BAR(); MM(1); BAR();
    // ph4: buf1 kh0 q0 | stage (t+2).P2 -> buf0 A.kh1
    LDB(1,0); LDA(1,0,0); if (more) STG2(0, t+2, 2);
    BAR(); MM(0); BAR();
    // ph5: buf1 kh0 q1 | stage (t+2).P3 -> buf0 B.kh1
    LDA(1,0,1); if (more) STG2(0, t+2, 3);
    BAR(); MM(1); BAR();
    // ph6: buf1 kh1 q0 | stage (t+3).P0 -> buf1 A.kh0
    LDB(1,1); LDA(1,1,0); if (more) STG2(1, t+3, 0);
    BAR(); MM(0); BAR();
    // ph7: buf1 kh1 q1 | stage (t+3).P1 -> buf1 B.kh0 | vouch tile t+2
    LDA(1,1,1);
    if (more){ STG2(1, t+3, 1); WAITV(4); }
    BAR(); MM(1); BAR();
  }

#undef STG2
#undef LDA
#undef LDB
#undef MM
#undef BAR
#undef WAITV

  const int col0 = n0 + wc*64 + 4*l16;   // lane's 4 columns: col0..col0+3
  const floatx4 bi = *reinterpret_cast<const floatx4*>(&bias[col0]);

  if (QKVMODE && n0 >= 2048){
    // V^T epilogue: vtb[bh][d][t], 4 consecutive t per lane -> packed 8B stores
    #pragma unroll
    for (int nt = 0; nt < 4; nt++){
      const int hd = col0 + nt - 2048;   // h*64 + d
      u16* vcol = vtb + (size_t)(hd >> 6) * 131072 + (size_t)(hd & 63) * 2048;
      #pragma unroll
      for (int i = 0; i < 8; i++){
        const int t0 = m0 + wr*128 + i*16 + ql*4;    // global row (b,t)
        const int bb = t0 >> 11, tt = t0 & 2047;
        short4v pk;
        #pragma unroll
        for (int r = 0; r < 4; r++) pk[r] = (short)f2b(acc[i][nt][r] + bi[nt]);
        *reinterpret_cast<short4v*>(vcol + (size_t)bb * 2097152 + tt) = pk;
      }
    }
    return;
  }

  #pragma unroll
  for (int i = 0; i < 8; i++){
    #pragma unroll
    for (int r = 0; r < 4; r++){
      const int row = m0 + wr*128 + i*16 + ql*4 + r;
      if (OUTBF){
        short4v o;
        #pragma unroll
        for (int nt = 0; nt < 4; nt++){
          float val = acc[i][nt][r] + bi[nt];
          if (GELU){
            const float t = 0.7978845608028654f * (val + 0.044715f * val * val * val);
            val = val / (1.f + __expf(-2.f * t));   // 0.5v(1+tanh t) == v*sigmoid(2t)
          }
          o[nt] = (short)f2b(val);
        }
        *reinterpret_cast<short4v*>(&outB[(size_t)row * N + col0]) = o;
      } else {
        floatx4 v;
        #pragma unroll
        for (int nt = 0; nt < 4; nt++) v[nt] = acc[i][nt][r] + bi[nt];
        if (RES){
          const floatx4 rr = *reinterpret_cast<const floatx4*>(&res[(size_t)row * N + col0]);
          #pragma unroll
          for (int nt = 0; nt < 4; nt++) v[nt] += rr[nt];
        }
        *reinterpret_cast<floatx4*>(&outF[(size_t)row * N + col0]) = v;
      }
    }
  }
}

// ---------------- flash attention (transposed-S), causal, D=64, H=16, T=2048 ----------------
// 128 Q-rows per block; length-balanced q-tile permutation; double-buffered K/V
// prefetch with ONE barrier per tile-iteration.
// grid (16, 64)
__global__ __launch_bounds__(256) void attn_kernel(
    const u16* __restrict__ qkv, const u16* __restrict__ vtb,
    u16* __restrict__ O)
{
  constexpr int T = 2048, LDQ = 3072, LDP = 72;
  __shared__ __attribute__((aligned(16))) u16 sK[2][2][64*32];
  __shared__ __attribute__((aligned(16))) u16 sV[2][2][64*32];
  __shared__ __attribute__((aligned(16))) u16 sP[4][16*LDP];

  const int tid = threadIdx.x, wave = tid >> 6, lane = tid & 63;
  const int quad = lane >> 4, l16 = lane & 15;

  const int lin = blockIdx.y * 16 + blockIdx.x;
  const int j = lin & 15;
  const int bh = lin >> 4;              // 0..63 (head slot)
  const int kk4 = bh >> 4;              // 0..3
  const int jj = (j + ((kk4 & 2) << 2)) & 15;
  const int qt = (kk4 & 1) ? (15 - jj) : jj;
  const int q0 = qt * 128;
  const int b = bh >> 4, h = bh & 15;

  const u16* Qp = qkv + (size_t)b * T * LDQ + h * 64;
  const u16* Kp = Qp + 1024;
  const u16* Vt = vtb + (size_t)bh * 64 * T;

  const int qx = (quad ^ ((l16 >> 1) & 3)) * 8;       // swizzled fragment chunk

  int qg[2]; qg[0] = q0 + wave*16 + l16; qg[1] = qg[0] + 64;
  short8 qf[2][2];
  #pragma unroll
  for (int g = 0; g < 2; g++){
    qf[g][0] = *reinterpret_cast<const short8*>(&Qp[(size_t)qg[g]*LDQ + quad*8]);
    qf[g][1] = *reinterpret_cast<const short8*>(&Qp[(size_t)qg[g]*LDQ + 32 + quad*8]);
  }

  float m_i[2] = {-INFINITY, -INFINITY}, l_i[2] = {0.f, 0.f};
  floatx4 o_acc[2][4];
  #pragma unroll
  for (int g = 0; g < 2; g++)
    #pragma unroll
    for (int nt = 0; nt < 4; nt++) o_acc[g][nt] = floatx4{0.f,0.f,0.f,0.f};

  const int srow = wave*16 + (lane >> 2);
  const int scol = ((lane & 3) ^ ((lane >> 3) & 3)) * 8;
  const int asrc = (lane & 48) | (quad * 4);   // shfl source: lane owning q-row quad*4+r

  const int kend = q0 + 128;

  // prefetch tile 0 into buf 0
  {
    glds16(Kp + (size_t)srow*LDQ + scol,      sK[0][0] + wave*512);
    glds16(Kp + (size_t)srow*LDQ + 32 + scol, sK[0][1] + wave*512);
    glds16(Vt + (size_t)srow*T + scol,        sV[0][0] + wave*512);
    glds16(Vt + (size_t)srow*T + 32 + scol,   sV[0][1] + wave*512);
  }

  int buf = 0;
  for (int k0 = 0; k0 < kend; k0 += 64, buf ^= 1){
    __syncthreads();   // staged tile `buf` ready; all waves past reads of buf^1
    if (k0 + 64 < kend){
      const int kn = k0 + 64;
      glds16(Kp + (size_t)(kn + srow)*LDQ + scol,      sK[buf^1][0] + wave*512);
      glds16(Kp + (size_t)(kn + srow)*LDQ + 32 + scol, sK[buf^1][1] + wave*512);
      glds16(Vt + (size_t)srow*T + kn + scol,          sV[buf^1][0] + wave*512);
      glds16(Vt + (size_t)srow*T + kn + 32 + scol,     sV[buf^1][1] + wave*512);
    }

    #pragma unroll
    for (int g = 0; g < 2; g++){
      if (g == 0 && k0 > q0) continue;   // tile fully masked for group 0

      // S^T = K·Q^T : s[sub][r] = score(key = k0+sub*16+quad*4+r, q = qg[g])
      float s[4][4];
      #pragma unroll
      for (int sub = 0; sub < 4; sub++){
        floatx4 sa = floatx4{0.f,0.f,0.f,0.f};
        const short8 kf0 = *reinterpret_cast<const short8*>(&sK[buf][0][(sub*16 + l16)*32 + qx]);
        const short8 kf1 = *reinterpret_cast<const short8*>(&sK[buf][1][(sub*16 + l16)*32 + qx]);
        sa = MFMA16(kf0, qf[g][0], sa);
        sa = MFMA16(kf1, qf[g][1], sa);
        #pragma unroll
        for (int r = 0; r < 4; r++) s[sub][r] = sa[r];
      }
      if (k0 == q0 + g*64){   // diagonal tile for this group
        #pragma unroll
        for (int sub = 0; sub < 4; sub++)
          #pragma unroll
          for (int r = 0; r < 4; r++){
            const int kidx = k0 + sub*16 + quad*4 + r;
            if (kidx > qg[g]) s[sub][r] = -1e30f;
          }
      }

      // in-lane softmax over 16 scores; cross-quad reduce with 2 shuffles
      float mx = s[0][0];
      #pragma unroll
      for (int sub = 0; sub < 4; sub++)
        #pragma unroll
        for (int r = 0; r < 4; r++) mx = fmaxf(mx, s[sub][r]);
      mx = fmaxf(mx, __shfl_xor(mx, 16));
      mx = fmaxf(mx, __shfl_xor(mx, 32));
      const float mnew  = fmaxf(m_i[g], mx);
      const float alpha = __expf(0.125f * (m_i[g] - mnew));
      float p[4][4], rowsum = 0.f;
      #pragma unroll
      for (int sub = 0; sub < 4; sub++)
        #pragma unroll
        for (int r = 0; r < 4; r++){
          p[sub][r] = __expf(0.125f * (s[sub][r] - mnew));
          rowsum += p[sub][r];
        }
      rowsum += __shfl_xor(rowsum, 16);
      rowsum += __shfl_xor(rowsum, 32);
      l_i[g] = l_i[g] * alpha + rowsum;
      m_i[g] = mnew;

      float arow[4];
      #pragma unroll
      for (int r = 0; r < 4; r++) arow[r] = __shfl(alpha, asrc + r);
      #pragma unroll
      for (int nt = 0; nt < 4; nt++)
        #pragma unroll
        for (int r = 0; r < 4; r++) o_acc[g][nt][r] *= arow[r];

      // P -> sP in A-layout (row = q = l16, cols = key)
      #pragma unroll
      for (int sub = 0; sub < 4; sub++){
        short4v pk;
        pk[0] = (short)f2b(p[sub][0]); pk[1] = (short)f2b(p[sub][1]);
        pk[2] = (short)f2b(p[sub][2]); pk[3] = (short)f2b(p[sub][3]);
        *reinterpret_cast<short4v*>(&sP[wave][l16*LDP + sub*16 + quad*4]) = pk;
      }
      const short8 pf0 = *reinterpret_cast<const short8*>(&sP[wave][l16*LDP + quad*8]);
      const short8 pf1 = *reinterpret_cast<const short8*>(&sP[wave][l16*LDP + 32 + quad*8]);
      #pragma unroll
      for (int nt = 0; nt < 4; nt++){
        const short8 vf0 = *reinterpret_cast<const short8*>(&sV[buf][0][(nt*16 + l16)*32 + qx]);
        const short8 vf1 = *reinterpret_cast<const short8*>(&sV[buf][1][(nt*16 + l16)*32 + qx]);
        o_acc[g][nt] = MFMA16(pf0, vf0, o_acc[g][nt]);
        o_acc[g][nt] = MFMA16(pf1, vf1, o_acc[g][nt]);
      }
    }
  }

  #pragma unroll
  for (int g = 0; g < 2; g++){
    float lrow[4];
    #pragma unroll
    for (int r = 0; r < 4; r++) lrow[r] = __shfl(l_i[g], asrc + r);
    #pragma unroll
    for (int nt = 0; nt < 4; nt++){
      #pragma unroll
      for (int r = 0; r < 4; r++){
        const int row = q0 + g*64 + wave*16 + quad*4 + r;
        O[(size_t)(b*T + row)*1024 + h*64 + nt*16 + l16] = f2b(o_acc[g][nt][r] / lrow[r]);
      }
    }
  }
}

// ---------------- launch ----------------
extern "C" void kernel_launch(void* const* d_in, const int* in_sizes, int n_in,
                              void* d_out, int out_size, void* d_ws, size_t ws_size,
                              hipStream_t stream){
  const float* x      = (const float*)d_in[0];
  const float* Wq     = (const float*)d_in[1];
  const float* bq     = (const float*)d_in[2];
  const float* Wk     = (const float*)d_in[3];
  const float* bk     = (const float*)d_in[4];
  const float* Wv     = (const float*)d_in[5];
  const float* bv     = (const float*)d_in[6];
  const float* Wo     = (const float*)d_in[7];
  const float* bo     = (const float*)d_in[8];
  const float* ln1_g  = (const float*)d_in[9];
  const float* ln1_b  = (const float*)d_in[10];
  const float* ln2_g  = (const float*)d_in[11];
  const float* ln2_b  = (const float*)d_in[12];
  const float* W_fc   = (const float*)d_in[13];
  const float* b_fc   = (const float*)d_in[14];
  const float* W_proj = (const float*)d_in[15];
  const float* b_proj = (const float*)d_in[16];
  float* out = (float*)d_out;
  char* ws = (char*)d_ws;
  const size_t MB = 1024 * 1024;

  u16* bufA  = (u16*)(ws);            // 16MB: xn -> attn_out -> h  [8192][1024]
  u16* qkvb  = (u16*)(ws + 16*MB);    // 48MB: [8192][3072] (V third unused)
  u16* vtb   = (u16*)(ws + 64*MB);    // 16MB: [64][64][2048] (written by QKV GEMM)
  u16* fcb   = (u16*)(ws + 16*MB);    // 64MB, reuses qkvb+vtb (dead after attn)
  float* x2  = out;                   // d_out doubles as fp32 residual buffer
  u16* Wqkvt = (u16*)(ws + 80*MB);    // 6MB: [3072][1024]
  u16* Wot   = (u16*)(ws + 86*MB);    // 2MB
  u16* Wfct  = (u16*)(ws + 88*MB);    // 8MB
  u16* Wpjt  = (u16*)(ws + 96*MB);    // 8MB
  float* bqkv= (float*)(ws + 104*MB); // 12KB

  dim3 tb(256), tg(512);
  transpose_cvt<<<dim3(32, 32),  tb, 0, stream>>>(Wq,     Wqkvt,             1024, 1024);
  transpose_cvt<<<dim3(32, 32),  tb, 0, stream>>>(Wk,     Wqkvt + 1024*1024, 1024, 1024);
  transpose_cvt<<<dim3(32, 32),  tb, 0, stream>>>(Wv,     Wqkvt + 2048*1024, 1024, 1024);
  transpose_cvt<<<dim3(32, 32),  tb, 0, stream>>>(Wo,     Wot,               1024, 1024);
  transpose_cvt<<<dim3(128, 32), tb, 0, stream>>>(W_fc,   Wfct,              1024, 4096);
  transpose_cvt<<<dim3(32, 128), tb, 0, stream>>>(W_proj, Wpjt,              4096, 1024);
  bias_concat<<<dim3(12), tb, 0, stream>>>(bq, bk, bv, bqkv);

  ln_kernel<<<8192, tb, 0, stream>>>(x, ln1_g, ln1_b, bufA);

  // fused QKV: [8192,1024] @ [3072,1024]^T -> Q,K into qkvb; V^T into vtb
  gemm256<false,false,true,true><<<dim3(32,12), tg, 0, stream>>>(
      bufA, Wqkvt, bqkv, nullptr, nullptr, qkvb, vtb, 8192, 3072, 1024);

  attn_kernel<<<dim3(16, 64), tb, 0, stream>>>(qkvb, vtb, bufA);

  gemm256<false,true,false,false><<<dim3(32,4), tg, 0, stream>>>(
      bufA, Wot, bo, x, x2, nullptr, nullptr, 8192, 1024, 1024);

  ln_kernel<<<8192, tb, 0, stream>>>(x2, ln2_g, ln2_b, bufA);

  gemm256<true,false,true,false><<<dim3(32,16), tg, 0, stream>>>(
      bufA, Wfct, b_fc, nullptr, nullptr, fcb, nullptr, 8192, 4096, 1024);

  gemm256<false,true,false,false><<<dim3(32,4), tg, 0, stream>>>(
      fcb, Wpjt, b_proj, x2, out, nullptr, nullptr, 8192, 1024, 4096);
}

// Round 4
// 540.463 us; speedup vs baseline: 1.1111x; 1.1111x over previous
//
#include <hip/hip_runtime.h>

typedef __attribute__((ext_vector_type(8))) short short8;
typedef __attribute__((ext_vector_type(4))) short short4v;
typedef __attribute__((ext_vector_type(4))) float floatx4;
typedef unsigned short u16;

#define MFMA16(a,b,c) __builtin_amdgcn_mfma_f32_16x16x32_bf16(a,b,c,0,0,0)

typedef const __attribute__((address_space(1))) void* gas1;
typedef __attribute__((address_space(3))) void* las3;
static __device__ __forceinline__ void glds16(const void* g, void* l){
  __builtin_amdgcn_global_load_lds((gas1)g, (las3)l, 16, 0, 0);
}

// fp32 -> bf16 round-to-nearest-even
static __device__ __forceinline__ u16 f2b(float f){
  union { float f; unsigned int u; } c; c.f = f;
  unsigned int u = c.u;
  u += 0x7fffu + ((u >> 16) & 1u);
  return (u16)(u >> 16);
}

// ---------------- fused prep: 6 weight transposes (fp32->bf16) + bias concat --------
// One launch replaces 7. Block id selects matrix + 32x32 tile; body identical to the
// proven transpose_cvt. id==12288 does the 3072-elem bias concat.
__global__ __launch_bounds__(256) void prep_kernel(
    const float* __restrict__ Wq, const float* __restrict__ Wk,
    const float* __restrict__ Wv, const float* __restrict__ Wo,
    const float* __restrict__ Wfc, const float* __restrict__ Wpj,
    u16* __restrict__ Wqkvt, u16* __restrict__ Wot,
    u16* __restrict__ Wfct, u16* __restrict__ Wpjt,
    const float* __restrict__ bq, const float* __restrict__ bk,
    const float* __restrict__ bv, float* __restrict__ bqkv)
{
  const int id = blockIdx.x;
  if (id == 12288){
    for (int i = threadIdx.x; i < 3072; i += 256)
      bqkv[i] = i < 1024 ? bq[i] : (i < 2048 ? bk[i - 1024] : bv[i - 2048]);
    return;
  }
  const float* W; u16* Wt; int K, N, loc, tshift;
  if (id < 4096){
    K = 1024; N = 1024; loc = id & 1023; tshift = 5;
    const int w = id >> 10;
    W  = (w == 0) ? Wq : (w == 1) ? Wk : (w == 2) ? Wv : Wo;
    Wt = (w == 3) ? Wot : Wqkvt + (size_t)w * 1024 * 1024;
  } else if (id < 8192){
    K = 1024; N = 4096; loc = id - 4096; tshift = 7; W = Wfc; Wt = Wfct;
  } else {
    K = 4096; N = 1024; loc = id - 8192; tshift = 5; W = Wpj; Wt = Wpjt;
  }
  const int nx = (loc & ((1 << tshift) - 1)) * 32;
  const int kx = (loc >> tshift) * 32;
  __shared__ float tile[32][33];
  const int tx = threadIdx.x & 31, ty = threadIdx.x >> 5;
  #pragma unroll
  for (int i = ty; i < 32; i += 8)
    tile[i][tx] = W[(size_t)(kx + i) * N + nx + tx];
  __syncthreads();
  #pragma unroll
  for (int i = ty; i < 32; i += 8)
    Wt[(size_t)(nx + i) * K + kx + tx] = f2b(tile[tx][i]);
}

// ---------------- layernorm fp32 -> bf16, C=1024, 1 block/row ----------------
__global__ __launch_bounds__(256) void ln_kernel(
    const float* __restrict__ x, const float* __restrict__ g,
    const float* __restrict__ b, u16* __restrict__ out){
  const int row = blockIdx.x, tid = threadIdx.x;
  const float4 v = reinterpret_cast<const float4*>(x + (size_t)row * 1024)[tid];
  float s  = v.x + v.y + v.z + v.w;
  float s2 = v.x*v.x + v.y*v.y + v.z*v.z + v.w*v.w;
  #pragma unroll
  for (int off = 1; off < 64; off <<= 1){
    s  += __shfl_xor(s,  off);
    s2 += __shfl_xor(s2, off);
  }
  __shared__ float red[8];
  const int wave = tid >> 6, lane = tid & 63;
  if (lane == 0){ red[wave] = s; red[4 + wave] = s2; }
  __syncthreads();
  s  = red[0] + red[1] + red[2] + red[3];
  s2 = red[4] + red[5] + red[6] + red[7];
  const float mu  = s * (1.f/1024.f);
  const float var = s2 * (1.f/1024.f) - mu * mu;
  const float rs  = rsqrtf(var + 1e-5f);
  const float4 gg = reinterpret_cast<const float4*>(g)[tid];
  const float4 bb = reinterpret_cast<const float4*>(b)[tid];
  ushort4 o;
  o.x = f2b((v.x - mu) * rs * gg.x + bb.x);
  o.y = f2b((v.y - mu) * rs * gg.y + bb.y);
  o.z = f2b((v.z - mu) * rs * gg.z + bb.z);
  o.w = f2b((v.w - mu) * rs * gg.w + bb.w);
  reinterpret_cast<ushort4*>(out + (size_t)row * 1024)[tid] = o;
}

// ---------------- GEMM: 128x128 tile, BK=32 double-buffered, permuted-B epilogue ------
// A: MxK bf16; Bt: NxK bf16; out = epilogue(A @ Bt^T + bias [+res]); K % 32 == 0.
// XOR bank swizzle: LDS slot (row, chunk c) holds global chunk (c ^ ((slotrow>>1)&3)).
// B rows are PERMUTED at staging: LDS slot nt*16+l16 holds global col 4*l16+nt of its
// 64-half, so each lane's 4 nt-accumulators are 4 ADJACENT columns -> packed stores.
// QKVMODE: blocks with n0>=2048 write V^T to vtb ([bh][d][t]); bias = concat qkv bias.
template<bool GELU, bool RES, bool OUTBF, bool QKVMODE>
__global__ __launch_bounds__(256) void gemm128(
    const u16* __restrict__ A, const u16* __restrict__ Bt,
    const float* __restrict__ bias,
    const float* __restrict__ res,
    float* __restrict__ outF, u16* __restrict__ outB,
    u16* __restrict__ vtb,
    int M, int N, int K)
{
  __shared__ __attribute__((aligned(16))) u16 sA[2][128 * 32];
  __shared__ __attribute__((aligned(16))) u16 sB[2][128 * 32];
  const int tid  = threadIdx.x;
  const int wave = tid >> 6, lane = tid & 63, quad = lane >> 4, l16 = lane & 15;
  const int m0 = blockIdx.x * 128, n0 = blockIdx.y * 128;
  const int wm = (wave >> 1) * 64, wn = (wave & 1) * 64;

  const int scol = ((lane & 3) ^ ((lane >> 3) & 3)) * 8;
  const size_t aoff  = (size_t)(m0 + wave*32 + (lane >> 2)) * K + scol;
  const size_t aoff2 = aoff + (size_t)16 * K;
  // permuted B rows: wave w, issue h stages global col n0+(w>>1)*64+4*(L>>2)+(w&1)*2+h
  const int brow = n0 + (wave >> 1)*64 + 4*(lane >> 2) + (wave & 1)*2;
  const size_t boff  = (size_t)brow * K + scol;
  const size_t boff2 = boff + (size_t)K;
  u16* alp = sA[0] + wave * 1024;
  u16* blp = sB[0] + wave * 1024;
  const int qx = (quad ^ ((l16 >> 1) & 3)) * 8;

  floatx4 acc[4][4];
  #pragma unroll
  for (int i = 0; i < 4; i++)
    #pragma unroll
    for (int nt = 0; nt < 4; nt++) acc[i][nt] = floatx4{0.f,0.f,0.f,0.f};

  // prefetch k0 = 0 into buf 0
  glds16(A  + aoff,  alp);
  glds16(A  + aoff2, alp + 512);
  glds16(Bt + boff,  blp);
  glds16(Bt + boff2, blp + 512);

  int buf = 0;
  for (int k0 = 0; k0 < K; k0 += 32, buf ^= 1){
    __syncthreads();   // buf's loads drained (issued one compute-phase ago); buf^1 free
    if (k0 + 32 < K){
      const int kn = k0 + 32;
      const int bo = (buf ^ 1) * 4096;
      glds16(A  + aoff  + kn, alp + bo);
      glds16(A  + aoff2 + kn, alp + bo + 512);
      glds16(Bt + boff  + kn, blp + bo);
      glds16(Bt + boff2 + kn, blp + bo + 512);
    }
    const u16* sa = sA[buf];
    const u16* sb = sB[buf];
    short8 af[4], bf[4];
    #pragma unroll
    for (int i = 0; i < 4; i++)
      af[i] = *reinterpret_cast<const short8*>(&sa[(wm + i*16 + l16)*32 + qx]);
    #pragma unroll
    for (int nt = 0; nt < 4; nt++)
      bf[nt] = *reinterpret_cast<const short8*>(&sb[(wn + nt*16 + l16)*32 + qx]);
    #pragma unroll
    for (int i = 0; i < 4; i++)
      #pragma unroll
      for (int nt = 0; nt < 4; nt++)
        acc[i][nt] = MFMA16(af[i], bf[nt], acc[i][nt]);
  }

  const int col0 = n0 + wn + 4*l16;   // lane's 4 columns: col0..col0+3
  const floatx4 bi = *reinterpret_cast<const floatx4*>(&bias[col0]);

  if (QKVMODE && n0 >= 2048){
    // V^T epilogue: vtb[bh][d][t], 4 consecutive t per lane -> packed 8B stores
    #pragma unroll
    for (int nt = 0; nt < 4; nt++){
      const int hd = col0 + nt - 2048;   // h*64 + d
      u16* vcol = vtb + (size_t)(hd >> 6) * 131072 + (size_t)(hd & 63) * 2048;
      #pragma unroll
      for (int i = 0; i < 4; i++){
        const int t0 = m0 + wm + i*16 + quad*4;      // global row (b,t)
        const int bb = t0 >> 11, tt = t0 & 2047;
        short4v pk;
        #pragma unroll
        for (int r = 0; r < 4; r++) pk[r] = (short)f2b(acc[i][nt][r] + bi[nt]);
        *reinterpret_cast<short4v*>(vcol + (size_t)bb * 2097152 + tt) = pk;
      }
    }
    return;
  }

  #pragma unroll
  for (int i = 0; i < 4; i++){
    #pragma unroll
    for (int r = 0; r < 4; r++){
      const int row = m0 + wm + i*16 + quad*4 + r;
      if (OUTBF){
        short4v o;
        #pragma unroll
        for (int nt = 0; nt < 4; nt++){
          float val = acc[i][nt][r] + bi[nt];
          if (GELU){
            const float t = 0.7978845608028654f * (val + 0.044715f * val * val * val);
            val = val / (1.f + __expf(-2.f * t));   // 0.5v(1+tanh t) == v*sigmoid(2t)
          }
          o[nt] = (short)f2b(val);
        }
        *reinterpret_cast<short4v*>(&outB[(size_t)row * N + col0]) = o;
      } else {
        floatx4 v;
        #pragma unroll
        for (int nt = 0; nt < 4; nt++) v[nt] = acc[i][nt][r] + bi[nt];
        if (RES){
          const floatx4 rr = *reinterpret_cast<const floatx4*>(&res[(size_t)row * N + col0]);
          #pragma unroll
          for (int nt = 0; nt < 4; nt++) v[nt] += rr[nt];
        }
        *reinterpret_cast<floatx4*>(&outF[(size_t)row * N + col0]) = v;
      }
    }
  }
}

// ---------------- flash attention (transposed-S), causal, D=64, H=16, T=2048 ----------------
// 128 Q-rows per block; length-balanced q-tile permutation; double-buffered K/V
// prefetch with ONE barrier per tile-iteration. T5: setprio(1) around MFMA clusters.
// grid (16, 64)
__global__ __launch_bounds__(256) void attn_kernel(
    const u16* __restrict__ qkv, const u16* __restrict__ vtb,
    u16* __restrict__ O)
{
  constexpr int T = 2048, LDQ = 3072, LDP = 72;
  __shared__ __attribute__((aligned(16))) u16 sK[2][2][64*32];
  __shared__ __attribute__((aligned(16))) u16 sV[2][2][64*32];
  __shared__ __attribute__((aligned(16))) u16 sP[4][16*LDP];

  const int tid = threadIdx.x, wave = tid >> 6, lane = tid & 63;
  const int quad = lane >> 4, l16 = lane & 15;

  const int lin = blockIdx.y * 16 + blockIdx.x;
  const int j = lin & 15;
  const int bh = lin >> 4;              // 0..63 (head slot)
  const int kk4 = bh >> 4;              // 0..3
  const int jj = (j + ((kk4 & 2) << 2)) & 15;
  const int qt = (kk4 & 1) ? (15 - jj) : jj;
  const int q0 = qt * 128;
  const int b = bh >> 4, h = bh & 15;

  const u16* Qp = qkv + (size_t)b * T * LDQ + h * 64;
  const u16* Kp = Qp + 1024;
  const u16* Vt = vtb + (size_t)bh * 64 * T;

  const int qx = (quad ^ ((l16 >> 1) & 3)) * 8;       // swizzled fragment chunk

  int qg[2]; qg[0] = q0 + wave*16 + l16; qg[1] = qg[0] + 64;
  short8 qf[2][2];
  #pragma unroll
  for (int g = 0; g < 2; g++){
    qf[g][0] = *reinterpret_cast<const short8*>(&Qp[(size_t)qg[g]*LDQ + quad*8]);
    qf[g][1] = *reinterpret_cast<const short8*>(&Qp[(size_t)qg[g]*LDQ + 32 + quad*8]);
  }

  float m_i[2] = {-INFINITY, -INFINITY}, l_i[2] = {0.f, 0.f};
  floatx4 o_acc[2][4];
  #pragma unroll
  for (int g = 0; g < 2; g++)
    #pragma unroll
    for (int nt = 0; nt < 4; nt++) o_acc[g][nt] = floatx4{0.f,0.f,0.f,0.f};

  const int srow = wave*16 + (lane >> 2);
  const int scol = ((lane & 3) ^ ((lane >> 3) & 3)) * 8;
  const int asrc = (lane & 48) | (quad * 4);   // shfl source: lane owning q-row quad*4+r

  const int kend = q0 + 128;

  // prefetch tile 0 into buf 0
  {
    glds16(Kp + (size_t)srow*LDQ + scol,      sK[0][0] + wave*512);
    glds16(Kp + (size_t)srow*LDQ + 32 + scol, sK[0][1] + wave*512);
    glds16(Vt + (size_t)srow*T + scol,        sV[0][0] + wave*512);
    glds16(Vt + (size_t)srow*T + 32 + scol,   sV[0][1] + wave*512);
  }

  int buf = 0;
  for (int k0 = 0; k0 < kend; k0 += 64, buf ^= 1){
    __syncthreads();   // staged tile `buf` ready; all waves past reads of buf^1
    if (k0 + 64 < kend){
      const int kn = k0 + 64;
      glds16(Kp + (size_t)(kn + srow)*LDQ + scol,      sK[buf^1][0] + wave*512);
      glds16(Kp + (size_t)(kn + srow)*LDQ + 32 + scol, sK[buf^1][1] + wave*512);
      glds16(Vt + (size_t)srow*T + kn + scol,          sV[buf^1][0] + wave*512);
      glds16(Vt + (size_t)srow*T + kn + 32 + scol,     sV[buf^1][1] + wave*512);
    }

    #pragma unroll
    for (int g = 0; g < 2; g++){
      if (g == 0 && k0 > q0) continue;   // tile fully masked for group 0

      // S^T = K·Q^T : s[sub][r] = score(key = k0+sub*16+quad*4+r, q = qg[g])
      float s[4][4];
      __builtin_amdgcn_s_setprio(1);
      #pragma unroll
      for (int sub = 0; sub < 4; sub++){
        floatx4 sa = floatx4{0.f,0.f,0.f,0.f};
        const short8 kf0 = *reinterpret_cast<const short8*>(&sK[buf][0][(sub*16 + l16)*32 + qx]);
        const short8 kf1 = *reinterpret_cast<const short8*>(&sK[buf][1][(sub*16 + l16)*32 + qx]);
        sa = MFMA16(kf0, qf[g][0], sa);
        sa = MFMA16(kf1, qf[g][1], sa);
        #pragma unroll
        for (int r = 0; r < 4; r++) s[sub][r] = sa[r];
      }
      __builtin_amdgcn_s_setprio(0);
      if (k0 == q0 + g*64){   // diagonal tile for this group
        #pragma unroll
        for (int sub = 0; sub < 4; sub++)
          #pragma unroll
          for (int r = 0; r < 4; r++){
            const int kidx = k0 + sub*16 + quad*4 + r;
            if (kidx > qg[g]) s[sub][r] = -1e30f;
          }
      }

      // in-lane softmax over 16 scores; cross-quad reduce with 2 shuffles
      float mx = s[0][0];
      #pragma unroll
      for (int sub = 0; sub < 4; sub++)
        #pragma unroll
        for (int r = 0; r < 4; r++) mx = fmaxf(mx, s[sub][r]);
      mx = fmaxf(mx, __shfl_xor(mx, 16));
      mx = fmaxf(mx, __shfl_xor(mx, 32));
      const float mnew  = fmaxf(m_i[g], mx);
      const float alpha = __expf(0.125f * (m_i[g] - mnew));
      float p[4][4], rowsum = 0.f;
      #pragma unroll
      for (int sub = 0; sub < 4; sub++)
        #pragma unroll
        for (int r = 0; r < 4; r++){
          p[sub][r] = __expf(0.125f * (s[sub][r] - mnew));
          rowsum += p[sub][r];
        }
      rowsum += __shfl_xor(rowsum, 16);
      rowsum += __shfl_xor(rowsum, 32);
      l_i[g] = l_i[g] * alpha + rowsum;
      m_i[g] = mnew;

      float arow[4];
      #pragma unroll
      for (int r = 0; r < 4; r++) arow[r] = __shfl(alpha, asrc + r);
      #pragma unroll
      for (int nt = 0; nt < 4; nt++)
        #pragma unroll
        for (int r = 0; r < 4; r++) o_acc[g][nt][r] *= arow[r];

      // P -> sP in A-layout (row = q = l16, cols = key); per-wave buffer,
      // reused across g: safe, a wave's DS ops execute in order.
      #pragma unroll
      for (int sub = 0; sub < 4; sub++){
        short4v pk;
        pk[0] = (short)f2b(p[sub][0]); pk[1] = (short)f2b(p[sub][1]);
        pk[2] = (short)f2b(p[sub][2]); pk[3] = (short)f2b(p[sub][3]);
        *reinterpret_cast<short4v*>(&sP[wave][l16*LDP + sub*16 + quad*4]) = pk;
      }
      const short8 pf0 = *reinterpret_cast<const short8*>(&sP[wave][l16*LDP + quad*8]);
      const short8 pf1 = *reinterpret_cast<const short8*>(&sP[wave][l16*LDP + 32 + quad*8]);
      __builtin_amdgcn_s_setprio(1);
      #pragma unroll
      for (int nt = 0; nt < 4; nt++){
        const short8 vf0 = *reinterpret_cast<const short8*>(&sV[buf][0][(nt*16 + l16)*32 + qx]);
        const short8 vf1 = *reinterpret_cast<const short8*>(&sV[buf][1][(nt*16 + l16)*32 + qx]);
        o_acc[g][nt] = MFMA16(pf0, vf0, o_acc[g][nt]);
        o_acc[g][nt] = MFMA16(pf1, vf1, o_acc[g][nt]);
      }
      __builtin_amdgcn_s_setprio(0);
    }
  }

  #pragma unroll
  for (int g = 0; g < 2; g++){
    float lrow[4];
    #pragma unroll
    for (int r = 0; r < 4; r++) lrow[r] = __shfl(l_i[g], asrc + r);
    #pragma unroll
    for (int nt = 0; nt < 4; nt++){
      #pragma unroll
      for (int r = 0; r < 4; r++){
        const int row = q0 + g*64 + wave*16 + quad*4 + r;
        O[(size_t)(b*T + row)*1024 + h*64 + nt*16 + l16] = f2b(o_acc[g][nt][r] / lrow[r]);
      }
    }
  }
}

// ---------------- launch ----------------
extern "C" void kernel_launch(void* const* d_in, const int* in_sizes, int n_in,
                              void* d_out, int out_size, void* d_ws, size_t ws_size,
                              hipStream_t stream){
  const float* x      = (const float*)d_in[0];
  const float* Wq     = (const float*)d_in[1];
  const float* bq     = (const float*)d_in[2];
  const float* Wk     = (const float*)d_in[3];
  const float* bk     = (const float*)d_in[4];
  const float* Wv     = (const float*)d_in[5];
  const float* bv     = (const float*)d_in[6];
  const float* Wo     = (const float*)d_in[7];
  const float* bo     = (const float*)d_in[8];
  const float* ln1_g  = (const float*)d_in[9];
  const float* ln1_b  = (const float*)d_in[10];
  const float* ln2_g  = (const float*)d_in[11];
  const float* ln2_b  = (const float*)d_in[12];
  const float* W_fc   = (const float*)d_in[13];
  const float* b_fc   = (const float*)d_in[14];
  const float* W_proj = (const float*)d_in[15];
  const float* b_proj = (const float*)d_in[16];
  float* out = (float*)d_out;
  char* ws = (char*)d_ws;
  const size_t MB = 1024 * 1024;

  u16* bufA  = (u16*)(ws);            // 16MB: xn -> attn_out -> h  [8192][1024]
  u16* qkvb  = (u16*)(ws + 16*MB);    // 48MB: [8192][3072] (V third unused)
  u16* vtb   = (u16*)(ws + 64*MB);    // 16MB: [64][64][2048] (written by QKV GEMM)
  u16* fcb   = (u16*)(ws + 16*MB);    // 64MB, reuses qkvb+vtb (dead after attn)
  float* x2  = out;                   // d_out doubles as fp32 residual buffer
  u16* Wqkvt = (u16*)(ws + 80*MB);    // 6MB: [3072][1024]
  u16* Wot   = (u16*)(ws + 86*MB);    // 2MB
  u16* Wfct  = (u16*)(ws + 88*MB);    // 8MB
  u16* Wpjt  = (u16*)(ws + 96*MB);    // 8MB
  float* bqkv= (float*)(ws + 104*MB); // 12KB

  dim3 tb(256);
  prep_kernel<<<dim3(12289), tb, 0, stream>>>(
      Wq, Wk, Wv, Wo, W_fc, W_proj, Wqkvt, Wot, Wfct, Wpjt, bq, bk, bv, bqkv);

  ln_kernel<<<8192, tb, 0, stream>>>(x, ln1_g, ln1_b, bufA);

  // fused QKV: [8192,1024] @ [3072,1024]^T -> Q,K into qkvb; V^T into vtb
  gemm128<false,false,true,true><<<dim3(64,24), tb, 0, stream>>>(
      bufA, Wqkvt, bqkv, nullptr, nullptr, qkvb, vtb, 8192, 3072, 1024);

  attn_kernel<<<dim3(16, 64), tb, 0, stream>>>(qkvb, vtb, bufA);

  gemm128<false,true,false,false><<<dim3(64,8), tb, 0, stream>>>(
      bufA, Wot, bo, x, x2, nullptr, nullptr, 8192, 1024, 1024);

  ln_kernel<<<8192, tb, 0, stream>>>(x2, ln2_g, ln2_b, bufA);

  gemm128<true,false,true,false><<<dim3(64,32), tb, 0, stream>>>(
      bufA, Wfct, b_fc, nullptr, nullptr, fcb, nullptr, 8192, 4096, 1024);

  gemm128<false,true,false,false><<<dim3(64,8), tb, 0, stream>>>(
      fcb, Wpjt, b_proj, x2, out, nullptr, nullptr, 8192, 1024, 4096);
}

// Round 5
// 532.730 us; speedup vs baseline: 1.1272x; 1.0145x over previous
//
#include <hip/hip_runtime.h>

typedef __attribute__((ext_vector_type(8))) short short8;
typedef __attribute__((ext_vector_type(4))) short short4v;
typedef __attribute__((ext_vector_type(4))) float floatx4;
typedef unsigned short u16;

#define MFMA16(a,b,c) __builtin_amdgcn_mfma_f32_16x16x32_bf16(a,b,c,0,0,0)

typedef const __attribute__((address_space(1))) void* gas1;
typedef __attribute__((address_space(3))) void* las3;
static __device__ __forceinline__ void glds16(const void* g, void* l){
  __builtin_amdgcn_global_load_lds((gas1)g, (las3)l, 16, 0, 0);
}

// fp32 -> bf16 round-to-nearest-even
static __device__ __forceinline__ u16 f2b(float f){
  union { float f; unsigned int u; } c; c.f = f;
  unsigned int u = c.u;
  u += 0x7fffu + ((u >> 16) & 1u);
  return (u16)(u >> 16);
}

// packed fp32x2 -> bf16x2 (RNE, same as f2b) in one instruction
static __device__ __forceinline__ unsigned int cvtpk(float lo, float hi){
  unsigned int r;
  asm("v_cvt_pk_bf16_f32 %0, %1, %2" : "=v"(r) : "v"(lo), "v"(hi));
  return r;
}

// ---------------- fused prep: 6 weight transposes (fp32->bf16) + bias concat --------
__global__ __launch_bounds__(256) void prep_kernel(
    const float* __restrict__ Wq, const float* __restrict__ Wk,
    const float* __restrict__ Wv, const float* __restrict__ Wo,
    const float* __restrict__ Wfc, const float* __restrict__ Wpj,
    u16* __restrict__ Wqkvt, u16* __restrict__ Wot,
    u16* __restrict__ Wfct, u16* __restrict__ Wpjt,
    const float* __restrict__ bq, const float* __restrict__ bk,
    const float* __restrict__ bv, float* __restrict__ bqkv)
{
  const int id = blockIdx.x;
  if (id == 12288){
    for (int i = threadIdx.x; i < 3072; i += 256)
      bqkv[i] = i < 1024 ? bq[i] : (i < 2048 ? bk[i - 1024] : bv[i - 2048]);
    return;
  }
  const float* W; u16* Wt; int K, N, loc, tshift;
  if (id < 4096){
    K = 1024; N = 1024; loc = id & 1023; tshift = 5;
    const int w = id >> 10;
    W  = (w == 0) ? Wq : (w == 1) ? Wk : (w == 2) ? Wv : Wo;
    Wt = (w == 3) ? Wot : Wqkvt + (size_t)w * 1024 * 1024;
  } else if (id < 8192){
    K = 1024; N = 4096; loc = id - 4096; tshift = 7; W = Wfc; Wt = Wfct;
  } else {
    K = 4096; N = 1024; loc = id - 8192; tshift = 5; W = Wpj; Wt = Wpjt;
  }
  const int nx = (loc & ((1 << tshift) - 1)) * 32;
  const int kx = (loc >> tshift) * 32;
  __shared__ float tile[32][33];
  const int tx = threadIdx.x & 31, ty = threadIdx.x >> 5;
  #pragma unroll
  for (int i = ty; i < 32; i += 8)
    tile[i][tx] = W[(size_t)(kx + i) * N + nx + tx];
  __syncthreads();
  #pragma unroll
  for (int i = ty; i < 32; i += 8)
    Wt[(size_t)(nx + i) * K + kx + tx] = f2b(tile[tx][i]);
}

// ---------------- layernorm fp32 -> bf16, C=1024, 1 block/row ----------------
__global__ __launch_bounds__(256) void ln_kernel(
    const float* __restrict__ x, const float* __restrict__ g,
    const float* __restrict__ b, u16* __restrict__ out){
  const int row = blockIdx.x, tid = threadIdx.x;
  const float4 v = reinterpret_cast<const float4*>(x + (size_t)row * 1024)[tid];
  float s  = v.x + v.y + v.z + v.w;
  float s2 = v.x*v.x + v.y*v.y + v.z*v.z + v.w*v.w;
  #pragma unroll
  for (int off = 1; off < 64; off <<= 1){
    s  += __shfl_xor(s,  off);
    s2 += __shfl_xor(s2, off);
  }
  __shared__ float red[8];
  const int wave = tid >> 6, lane = tid & 63;
  if (lane == 0){ red[wave] = s; red[4 + wave] = s2; }
  __syncthreads();
  s  = red[0] + red[1] + red[2] + red[3];
  s2 = red[4] + red[5] + red[6] + red[7];
  const float mu  = s * (1.f/1024.f);
  const float var = s2 * (1.f/1024.f) - mu * mu;
  const float rs  = rsqrtf(var + 1e-5f);
  const float4 gg = reinterpret_cast<const float4*>(g)[tid];
  const float4 bb = reinterpret_cast<const float4*>(b)[tid];
  ushort4 o;
  o.x = f2b((v.x - mu) * rs * gg.x + bb.x);
  o.y = f2b((v.y - mu) * rs * gg.y + bb.y);
  o.z = f2b((v.z - mu) * rs * gg.z + bb.z);
  o.w = f2b((v.w - mu) * rs * gg.w + bb.w);
  reinterpret_cast<ushort4*>(out + (size_t)row * 1024)[tid] = o;
}

// ---------------- GEMM: 128x128 tile, BK=32 double-buffered, permuted-B epilogue ------
template<bool GELU, bool RES, bool OUTBF, bool QKVMODE>
__global__ __launch_bounds__(256) void gemm128(
    const u16* __restrict__ A, const u16* __restrict__ Bt,
    const float* __restrict__ bias,
    const float* __restrict__ res,
    float* __restrict__ outF, u16* __restrict__ outB,
    u16* __restrict__ vtb,
    int M, int N, int K)
{
  __shared__ __attribute__((aligned(16))) u16 sA[2][128 * 32];
  __shared__ __attribute__((aligned(16))) u16 sB[2][128 * 32];
  const int tid  = threadIdx.x;
  const int wave = tid >> 6, lane = tid & 63, quad = lane >> 4, l16 = lane & 15;
  const int m0 = blockIdx.x * 128, n0 = blockIdx.y * 128;
  const int wm = (wave >> 1) * 64, wn = (wave & 1) * 64;

  const int scol = ((lane & 3) ^ ((lane >> 3) & 3)) * 8;
  const size_t aoff  = (size_t)(m0 + wave*32 + (lane >> 2)) * K + scol;
  const size_t aoff2 = aoff + (size_t)16 * K;
  const int brow = n0 + (wave >> 1)*64 + 4*(lane >> 2) + (wave & 1)*2;
  const size_t boff  = (size_t)brow * K + scol;
  const size_t boff2 = boff + (size_t)K;
  u16* alp = sA[0] + wave * 1024;
  u16* blp = sB[0] + wave * 1024;
  const int qx = (quad ^ ((l16 >> 1) & 3)) * 8;

  floatx4 acc[4][4];
  #pragma unroll
  for (int i = 0; i < 4; i++)
    #pragma unroll
    for (int nt = 0; nt < 4; nt++) acc[i][nt] = floatx4{0.f,0.f,0.f,0.f};

  // prefetch k0 = 0 into buf 0
  glds16(A  + aoff,  alp);
  glds16(A  + aoff2, alp + 512);
  glds16(Bt + boff,  blp);
  glds16(Bt + boff2, blp + 512);

  int buf = 0;
  for (int k0 = 0; k0 < K; k0 += 32, buf ^= 1){
    __syncthreads();
    if (k0 + 32 < K){
      const int kn = k0 + 32;
      const int bo = (buf ^ 1) * 4096;
      glds16(A  + aoff  + kn, alp + bo);
      glds16(A  + aoff2 + kn, alp + bo + 512);
      glds16(Bt + boff  + kn, blp + bo);
      glds16(Bt + boff2 + kn, blp + bo + 512);
    }
    const u16* sa = sA[buf];
    const u16* sb = sB[buf];
    short8 af[4], bf[4];
    #pragma unroll
    for (int i = 0; i < 4; i++)
      af[i] = *reinterpret_cast<const short8*>(&sa[(wm + i*16 + l16)*32 + qx]);
    #pragma unroll
    for (int nt = 0; nt < 4; nt++)
      bf[nt] = *reinterpret_cast<const short8*>(&sb[(wn + nt*16 + l16)*32 + qx]);
    #pragma unroll
    for (int i = 0; i < 4; i++)
      #pragma unroll
      for (int nt = 0; nt < 4; nt++)
        acc[i][nt] = MFMA16(af[i], bf[nt], acc[i][nt]);
  }

  const int col0 = n0 + wn + 4*l16;   // lane's 4 columns: col0..col0+3
  const floatx4 bi = *reinterpret_cast<const floatx4*>(&bias[col0]);

  if (QKVMODE && n0 >= 2048){
    // V^T epilogue: vtb[bh][d][t], 4 consecutive t per lane -> packed 8B stores
    #pragma unroll
    for (int nt = 0; nt < 4; nt++){
      const int hd = col0 + nt - 2048;   // h*64 + d
      u16* vcol = vtb + (size_t)(hd >> 6) * 131072 + (size_t)(hd & 63) * 2048;
      #pragma unroll
      for (int i = 0; i < 4; i++){
        const int t0 = m0 + wm + i*16 + quad*4;      // global row (b,t)
        const int bb = t0 >> 11, tt = t0 & 2047;
        short4v pk;
        #pragma unroll
        for (int r = 0; r < 4; r++) pk[r] = (short)f2b(acc[i][nt][r] + bi[nt]);
        *reinterpret_cast<short4v*>(vcol + (size_t)bb * 2097152 + tt) = pk;
      }
    }
    return;
  }

  #pragma unroll
  for (int i = 0; i < 4; i++){
    #pragma unroll
    for (int r = 0; r < 4; r++){
      const int row = m0 + wm + i*16 + quad*4 + r;
      if (OUTBF){
        short4v o;
        #pragma unroll
        for (int nt = 0; nt < 4; nt++){
          float val = acc[i][nt][r] + bi[nt];
          if (GELU){
            const float t = 0.7978845608028654f * (val + 0.044715f * val * val * val);
            val = val / (1.f + __expf(-2.f * t));   // 0.5v(1+tanh t) == v*sigmoid(2t)
          }
          o[nt] = (short)f2b(val);
        }
        *reinterpret_cast<short4v*>(&outB[(size_t)row * N + col0]) = o;
      } else {
        floatx4 v;
        #pragma unroll
        for (int nt = 0; nt < 4; nt++) v[nt] = acc[i][nt][r] + bi[nt];
        if (RES){
          const floatx4 rr = *reinterpret_cast<const floatx4*>(&res[(size_t)row * N + col0]);
          #pragma unroll
          for (int nt = 0; nt < 4; nt++) v[nt] += rr[nt];
        }
        *reinterpret_cast<floatx4*>(&outF[(size_t)row * N + col0]) = v;
      }
    }
  }
}

// ---------------- flash attention (transposed-S), causal, D=64, H=16, T=2048 ----------------
// 128 Q-rows per block; length-balanced q-tile permutation; double-buffered K/V.
// VALU-diet softmax: exp2 w/ folded scale, T13 defer-max (skip rescale unless
// max grows > 32 raw = 4 in exponent domain), packed bf16 converts, tree reduces.
// grid (16, 64)
__global__ __launch_bounds__(256) void attn_kernel(
    const u16* __restrict__ qkv, const u16* __restrict__ vtb,
    u16* __restrict__ O)
{
  constexpr int T = 2048, LDQ = 3072, LDP = 72;
  constexpr float CE = 0.18033688011112042f;   // 0.125 * log2(e)
  __shared__ __attribute__((aligned(16))) u16 sK[2][2][64*32];
  __shared__ __attribute__((aligned(16))) u16 sV[2][2][64*32];
  __shared__ __attribute__((aligned(16))) u16 sP[4][16*LDP];

  const int tid = threadIdx.x, wave = tid >> 6, lane = tid & 63;
  const int quad = lane >> 4, l16 = lane & 15;

  const int lin = blockIdx.y * 16 + blockIdx.x;
  const int j = lin & 15;
  const int bh = lin >> 4;              // 0..63 (head slot)
  const int kk4 = bh >> 4;              // 0..3
  const int jj = (j + ((kk4 & 2) << 2)) & 15;
  const int qt = (kk4 & 1) ? (15 - jj) : jj;
  const int q0 = qt * 128;
  const int b = bh >> 4, h = bh & 15;

  const u16* Qp = qkv + (size_t)b * T * LDQ + h * 64;
  const u16* Kp = Qp + 1024;
  const u16* Vt = vtb + (size_t)bh * 64 * T;

  const int qx = (quad ^ ((l16 >> 1) & 3)) * 8;       // swizzled fragment chunk

  int qg[2]; qg[0] = q0 + wave*16 + l16; qg[1] = qg[0] + 64;
  short8 qf[2][2];
  #pragma unroll
  for (int g = 0; g < 2; g++){
    qf[g][0] = *reinterpret_cast<const short8*>(&Qp[(size_t)qg[g]*LDQ + quad*8]);
    qf[g][1] = *reinterpret_cast<const short8*>(&Qp[(size_t)qg[g]*LDQ + 32 + quad*8]);
  }

  float m_i[2] = {-INFINITY, -INFINITY}, l_i[2] = {0.f, 0.f};
  floatx4 o_acc[2][4];
  #pragma unroll
  for (int g = 0; g < 2; g++)
    #pragma unroll
    for (int nt = 0; nt < 4; nt++) o_acc[g][nt] = floatx4{0.f,0.f,0.f,0.f};

  const int srow = wave*16 + (lane >> 2);
  const int scol = ((lane & 3) ^ ((lane >> 3) & 3)) * 8;
  const int asrc = (lane & 48) | (quad * 4);   // shfl source: lane owning q-row quad*4+r

  const int kend = q0 + 128;

  // prefetch tile 0 into buf 0
  {
    glds16(Kp + (size_t)srow*LDQ + scol,      sK[0][0] + wave*512);
    glds16(Kp + (size_t)srow*LDQ + 32 + scol, sK[0][1] + wave*512);
    glds16(Vt + (size_t)srow*T + scol,        sV[0][0] + wave*512);
    glds16(Vt + (size_t)srow*T + 32 + scol,   sV[0][1] + wave*512);
  }

  int buf = 0;
  for (int k0 = 0; k0 < kend; k0 += 64, buf ^= 1){
    __syncthreads();   // staged tile `buf` ready; all waves past reads of buf^1
    if (k0 + 64 < kend){
      const int kn = k0 + 64;
      glds16(Kp + (size_t)(kn + srow)*LDQ + scol,      sK[buf^1][0] + wave*512);
      glds16(Kp + (size_t)(kn + srow)*LDQ + 32 + scol, sK[buf^1][1] + wave*512);
      glds16(Vt + (size_t)srow*T + kn + scol,          sV[buf^1][0] + wave*512);
      glds16(Vt + (size_t)srow*T + kn + 32 + scol,     sV[buf^1][1] + wave*512);
    }

    #pragma unroll
    for (int g = 0; g < 2; g++){
      if (g == 0 && k0 > q0) continue;   // tile fully masked for group 0

      // S^T = K·Q^T : s[sub][r] = score(key = k0+sub*16+quad*4+r, q = qg[g])
      float s[4][4];
      __builtin_amdgcn_s_setprio(1);
      #pragma unroll
      for (int sub = 0; sub < 4; sub++){
        floatx4 sa = floatx4{0.f,0.f,0.f,0.f};
        const short8 kf0 = *reinterpret_cast<const short8*>(&sK[buf][0][(sub*16 + l16)*32 + qx]);
        const short8 kf1 = *reinterpret_cast<const short8*>(&sK[buf][1][(sub*16 + l16)*32 + qx]);
        sa = MFMA16(kf0, qf[g][0], sa);
        sa = MFMA16(kf1, qf[g][1], sa);
        #pragma unroll
        for (int r = 0; r < 4; r++) s[sub][r] = sa[r];
      }
      __builtin_amdgcn_s_setprio(0);
      if (k0 == q0 + g*64){   // diagonal tile for this group
        #pragma unroll
        for (int sub = 0; sub < 4; sub++)
          #pragma unroll
          for (int r = 0; r < 4; r++){
            const int kidx = k0 + sub*16 + quad*4 + r;
            if (kidx > qg[g]) s[sub][r] = -1e30f;
          }
      }

      // tree max (depth 4, independent sub-chains; fmaxf nesting can fuse to v_max3)
      float sm[4];
      #pragma unroll
      for (int sub = 0; sub < 4; sub++)
        sm[sub] = fmaxf(fmaxf(s[sub][0], s[sub][1]), fmaxf(s[sub][2], s[sub][3]));
      float mx = fmaxf(fmaxf(sm[0], sm[1]), fmaxf(sm[2], sm[3]));
      mx = fmaxf(mx, __shfl_xor(mx, 16));
      mx = fmaxf(mx, __shfl_xor(mx, 32));

      // T13 defer-max: only rescale when the running max grows by > 32 (raw score
      // units; = 4 in the exp2 domain, so P <= 2^~5.8 — safe in bf16/f32).
      const bool up = mx > m_i[g] + 32.f;
      const float mnew = up ? mx : m_i[g];

      float p[4][4], rs[4];
      #pragma unroll
      for (int sub = 0; sub < 4; sub++){
        #pragma unroll
        for (int r = 0; r < 4; r++)
          p[sub][r] = __builtin_amdgcn_exp2f(CE * (s[sub][r] - mnew));
        rs[sub] = (p[sub][0] + p[sub][1]) + (p[sub][2] + p[sub][3]);
      }
      float rowsum = (rs[0] + rs[1]) + (rs[2] + rs[3]);
      rowsum += __shfl_xor(rowsum, 16);
      rowsum += __shfl_xor(rowsum, 32);

      if (__any(up)){                    // wave-uniform branch
        const float alpha = up ? __builtin_amdgcn_exp2f(CE * (m_i[g] - mnew)) : 1.f;
        float arow[4];
        #pragma unroll
        for (int r = 0; r < 4; r++) arow[r] = __shfl(alpha, asrc + r);
        #pragma unroll
        for (int nt = 0; nt < 4; nt++)
          #pragma unroll
          for (int r = 0; r < 4; r++) o_acc[g][nt][r] *= arow[r];
        l_i[g] *= alpha;
        m_i[g] = mnew;
      }
      l_i[g] += rowsum;

      // P -> sP in A-layout (row = q = l16, cols = key); packed bf16 converts
      #pragma unroll
      for (int sub = 0; sub < 4; sub++){
        uint2 pk2;
        pk2.x = cvtpk(p[sub][0], p[sub][1]);
        pk2.y = cvtpk(p[sub][2], p[sub][3]);
        *reinterpret_cast<uint2*>(&sP[wave][l16*LDP + sub*16 + quad*4]) = pk2;
      }
      const short8 pf0 = *reinterpret_cast<const short8*>(&sP[wave][l16*LDP + quad*8]);
      const short8 pf1 = *reinterpret_cast<const short8*>(&sP[wave][l16*LDP + 32 + quad*8]);
      __builtin_amdgcn_s_setprio(1);
      #pragma unroll
      for (int nt = 0; nt < 4; nt++){
        const short8 vf0 = *reinterpret_cast<const short8*>(&sV[buf][0][(nt*16 + l16)*32 + qx]);
        const short8 vf1 = *reinterpret_cast<const short8*>(&sV[buf][1][(nt*16 + l16)*32 + qx]);
        o_acc[g][nt] = MFMA16(pf0, vf0, o_acc[g][nt]);
        o_acc[g][nt] = MFMA16(pf1, vf1, o_acc[g][nt]);
      }
      __builtin_amdgcn_s_setprio(0);
    }
  }

  #pragma unroll
  for (int g = 0; g < 2; g++){
    float lrow[4];
    #pragma unroll
    for (int r = 0; r < 4; r++) lrow[r] = __shfl(l_i[g], asrc + r);
    #pragma unroll
    for (int nt = 0; nt < 4; nt++){
      #pragma unroll
      for (int r = 0; r < 4; r++){
        const int row = q0 + g*64 + wave*16 + quad*4 + r;
        O[(size_t)(b*T + row)*1024 + h*64 + nt*16 + l16] = f2b(o_acc[g][nt][r] / lrow[r]);
      }
    }
  }
}

// ---------------- launch ----------------
extern "C" void kernel_launch(void* const* d_in, const int* in_sizes, int n_in,
                              void* d_out, int out_size, void* d_ws, size_t ws_size,
                              hipStream_t stream){
  const float* x      = (const float*)d_in[0];
  const float* Wq     = (const float*)d_in[1];
  const float* bq     = (const float*)d_in[2];
  const float* Wk     = (const float*)d_in[3];
  const float* bk     = (const float*)d_in[4];
  const float* Wv     = (const float*)d_in[5];
  const float* bv     = (const float*)d_in[6];
  const float* Wo     = (const float*)d_in[7];
  const float* bo     = (const float*)d_in[8];
  const float* ln1_g  = (const float*)d_in[9];
  const float* ln1_b  = (const float*)d_in[10];
  const float* ln2_g  = (const float*)d_in[11];
  const float* ln2_b  = (const float*)d_in[12];
  const float* W_fc   = (const float*)d_in[13];
  const float* b_fc   = (const float*)d_in[14];
  const float* W_proj = (const float*)d_in[15];
  const float* b_proj = (const float*)d_in[16];
  float* out = (float*)d_out;
  char* ws = (char*)d_ws;
  const size_t MB = 1024 * 1024;

  u16* bufA  = (u16*)(ws);            // 16MB: xn -> attn_out -> h  [8192][1024]
  u16* qkvb  = (u16*)(ws + 16*MB);    // 48MB: [8192][3072] (V third unused)
  u16* vtb   = (u16*)(ws + 64*MB);    // 16MB: [64][64][2048] (written by QKV GEMM)
  u16* fcb   = (u16*)(ws + 16*MB);    // 64MB, reuses qkvb+vtb (dead after attn)
  float* x2  = out;                   // d_out doubles as fp32 residual buffer
  u16* Wqkvt = (u16*)(ws + 80*MB);    // 6MB: [3072][1024]
  u16* Wot   = (u16*)(ws + 86*MB);    // 2MB
  u16* Wfct  = (u16*)(ws + 88*MB);    // 8MB
  u16* Wpjt  = (u16*)(ws + 96*MB);    // 8MB
  float* bqkv= (float*)(ws + 104*MB); // 12KB

  dim3 tb(256);
  prep_kernel<<<dim3(12289), tb, 0, stream>>>(
      Wq, Wk, Wv, Wo, W_fc, W_proj, Wqkvt, Wot, Wfct, Wpjt, bq, bk, bv, bqkv);

  ln_kernel<<<8192, tb, 0, stream>>>(x, ln1_g, ln1_b, bufA);

  // fused QKV: [8192,1024] @ [3072,1024]^T -> Q,K into qkvb; V^T into vtb
  gemm128<false,false,true,true><<<dim3(64,24), tb, 0, stream>>>(
      bufA, Wqkvt, bqkv, nullptr, nullptr, qkvb, vtb, 8192, 3072, 1024);

  attn_kernel<<<dim3(16, 64), tb, 0, stream>>>(qkvb, vtb, bufA);

  gemm128<false,true,false,false><<<dim3(64,8), tb, 0, stream>>>(
      bufA, Wot, bo, x, x2, nullptr, nullptr, 8192, 1024, 1024);

  ln_kernel<<<8192, tb, 0, stream>>>(x2, ln2_g, ln2_b, bufA);

  gemm128<true,false,true,false><<<dim3(64,32), tb, 0, stream>>>(
      bufA, Wfct, b_fc, nullptr, nullptr, fcb, nullptr, 8192, 4096, 1024);

  gemm128<false,true,false,false><<<dim3(64,8), tb, 0, stream>>>(
      fcb, Wpjt, b_proj, x2, out, nullptr, nullptr, 8192, 1024, 4096);
}